// Round 3
// baseline (1218.828 us; speedup 1.0000x reference)
//
#include <hip/hip_runtime.h>

#define LL 256
#define DD 512

typedef _Float16 f16;
typedef _Float16 f16x4_t __attribute__((ext_vector_type(4)));
typedef _Float16 f16x8_t __attribute__((ext_vector_type(8)));
typedef float f32x4_t __attribute__((ext_vector_type(4)));

__device__ __forceinline__ f16x8_t cvt2(const float4 a, const float4 b) {
  f16x8_t v;
  v[0] = (f16)a.x; v[1] = (f16)a.y; v[2] = (f16)a.z; v[3] = (f16)a.w;
  v[4] = (f16)b.x; v[5] = (f16)b.y; v[6] = (f16)b.z; v[7] = (f16)b.w;
  return v;
}

// ---------------- prep: Wt[e][d] = (f16) W[d][e] ----------------
__global__ void k_prep(const float* __restrict__ W, f16* __restrict__ Wt) {
  __shared__ float t[64][65];
  int bx = blockIdx.x & 7;   // e tile
  int by = blockIdx.x >> 3;  // d tile
  int tx = threadIdx.x & 63, tg = threadIdx.x >> 6;
  for (int r = tg; r < 64; r += 4)
    t[r][tx] = W[(by * 64 + r) * DD + bx * 64 + tx];
  __syncthreads();
  for (int r = tg; r < 64; r += 4)
    Wt[(bx * 64 + r) * DD + by * 64 + tx] = (f16)t[tx][r];
}

// LDS region1 (128KB), time-shared:
//   phase 0: xb[2][128][64] f16 (2x16KB)
//   phase A: BP[2][256][64] f16 @0,32768 ; Y[2][256][64] f16 @65536,98304
//   phase A end..phase B: A_w[256 l][256 m] f16 (rows 512B)
// LDS region2 (16KB), time-shared:
//   phase A softmax: colred[2][256] @0, colmax[256] @2048, colinv[256] @3072 (f32)
//   phase B: YT[128 d][64 m] f16 (16KB)
//   epilogue: gp[2][256] @0, beta[256] @2048 (f32)

__global__ __launch_bounds__(512, 2)
void k_main(const float* __restrict__ gi, const float* __restrict__ gj,
            const f16* __restrict__ Wt, const float* __restrict__ wv,
            f16* __restrict__ slabs, float* __restrict__ out) {
  __shared__ __align__(16) char R1[131072];
  __shared__ __align__(16) char R2[16384];

  const int tid = threadIdx.x;
  const int lane = tid & 63;
  const int wave = tid >> 6;  // 0..7
  const int lq = lane & 15, lg = lane >> 4;

  // XCD-aware swizzle keeping (b,0),(b,1) on the same XCD chunk
  const int sb = blockIdx.x;
  const int wk = (sb & 7) * 128 + (sb >> 3);
  const int b = wk >> 1, side = wk & 1;
  const float* __restrict__ x = (side ? gj : gi) + (size_t)b * (LL * DD);
  const float* __restrict__ y = (side ? gi : gj) + (size_t)b * (LL * DD);
  f16* __restrict__ slab = slabs + (size_t)wk * (LL * DD);  // P then aliased as aT

  char* const R1c = R1;
  char* const R2c = R2;
  float* const colred = (float*)R2c;            // [2][256]
  float* const colmax = (float*)(R2c + 2048);
  float* const colinv = (float*)(R2c + 3072);
  float* const gp     = (float*)R2c;            // [2][256] (after YT dead)
  float* const betas  = (float*)(R2c + 2048);

  // ================= phase 0: P = x @ W  -> slab[l][e] (f16) =================
  // Pt-acc orientation: mfma(A=Wt rows e, B=x rows l): acc(e=lg*4+r, l=lq)
  // wave: wl2 = w&1 (l 64-range in half), we4 = w>>1 (e 128-range)
  {
    const int wl2 = wave & 1, we4 = wave >> 1;
    for (int lh = 0; lh < 2; ++lh) {
      f32x4_t acc[8][4];  // [ef][lf]
#pragma unroll
      for (int ef = 0; ef < 8; ++ef)
#pragma unroll
        for (int lf = 0; lf < 4; ++lf) acc[ef][lf] = (f32x4_t){0.f, 0.f, 0.f, 0.f};

      const int xrow = tid >> 2;          // 0..127
      const int xc4 = (tid & 3) * 16;     // f32 col base
      // prologue: stage s=0 into xb0
      {
        const float* src = x + (size_t)(lh * 128 + xrow) * DD + 0 + xc4;
        float4 a0 = *(const float4*)src, a1 = *(const float4*)(src + 4);
        float4 a2 = *(const float4*)(src + 8), a3 = *(const float4*)(src + 12);
        unsigned swz = (unsigned)(xrow & 7) << 4;
        *(f16x8_t*)(R1c + xrow * 128 + ((xc4 * 2) ^ swz)) = cvt2(a0, a1);
        *(f16x8_t*)(R1c + xrow * 128 + ((xc4 * 2 + 16) ^ swz)) = cvt2(a2, a3);
      }
      __syncthreads();

      for (int s = 0; s < 8; ++s) {
        char* xbc = R1c + (s & 1) * 16384;
        char* xbn = R1c + ((s + 1) & 1) * 16384;
        float4 p0, p1, p2, p3;
        if (s < 7) {
          const float* src = x + (size_t)(lh * 128 + xrow) * DD + (s + 1) * 64 + xc4;
          p0 = *(const float4*)src; p1 = *(const float4*)(src + 4);
          p2 = *(const float4*)(src + 8); p3 = *(const float4*)(src + 12);
        }
#pragma unroll
        for (int ks = 0; ks < 2; ++ks) {
          f16x8_t wtF[8], xF[4];
#pragma unroll
          for (int ef = 0; ef < 8; ++ef) {
            int er = we4 * 128 + ef * 16 + lq;
            wtF[ef] = *(const f16x8_t*)(Wt + (size_t)er * DD + s * 64 + ks * 32 + lg * 8);
          }
#pragma unroll
          for (int lf = 0; lf < 4; ++lf) {
            int row = wl2 * 64 + lf * 16 + lq;
            xF[lf] = *(const f16x8_t*)(xbc + row * 128 +
                       ((ks * 64 + lg * 16) ^ ((unsigned)(row & 7) << 4)));
          }
#pragma unroll
          for (int ef = 0; ef < 8; ++ef)
#pragma unroll
            for (int lf = 0; lf < 4; ++lf)
              acc[ef][lf] = __builtin_amdgcn_mfma_f32_16x16x32_f16(wtF[ef], xF[lf], acc[ef][lf], 0, 0, 0);
        }
        if (s < 7) {
          unsigned swz = (unsigned)(xrow & 7) << 4;
          *(f16x8_t*)(xbn + xrow * 128 + ((xc4 * 2) ^ swz)) = cvt2(p0, p1);
          *(f16x8_t*)(xbn + xrow * 128 + ((xc4 * 2 + 16) ^ swz)) = cvt2(p2, p3);
        }
        __syncthreads();
      }
      // writeback P-half: slab[l][e], b64 per tile
#pragma unroll
      for (int ef = 0; ef < 8; ++ef)
#pragma unroll
        for (int lf = 0; lf < 4; ++lf) {
          int l = lh * 128 + wl2 * 64 + lf * 16 + lq;
          int e = we4 * 128 + ef * 16 + lg * 4;
          f16x4_t v;
          v[0] = (f16)acc[ef][lf][0]; v[1] = (f16)acc[ef][lf][1];
          v[2] = (f16)acc[ef][lf][2]; v[3] = (f16)acc[ef][lf][3];
          *(f16x4_t*)(slab + (size_t)l * DD + e) = v;
        }
    }
  }
  __syncthreads();  // P-slab stores drained before phase A reads

  // ======== phase A: St = y @ P^T  (acc(m=lg*4+r, l=lq)), full S in regs ========
  // wave: wm = w&3 (m 64-range), wl = w>>2 (l 128-range)
  {
    const int wm = wave & 3, wl = wave >> 2;
    f32x4_t accS[4][8];  // [mf][nf]
#pragma unroll
    for (int mf = 0; mf < 4; ++mf)
#pragma unroll
      for (int nf = 0; nf < 8; ++nf) accS[mf][nf] = (f32x4_t){0.f, 0.f, 0.f, 0.f};

    const int prow = tid >> 1;          // 0..255 (l for BP, m for Y)
    const int phalf = tid & 1;          // which 32-elem half

    // prologue: stage 0
    {
      unsigned swz = (unsigned)(prow & 7) << 4;
#pragma unroll
      for (int q = 0; q < 4; ++q) {
        f16x8_t pv = *(const f16x8_t*)(slab + (size_t)prow * DD + phalf * 32 + q * 8);
        *(f16x8_t*)(R1c + prow * 128 + ((phalf * 64 + q * 16) ^ swz)) = pv;
      }
      const float* src = y + (size_t)prow * DD + phalf * 32;
#pragma unroll
      for (int q = 0; q < 4; ++q) {
        float4 a0 = *(const float4*)(src + q * 8);
        float4 a1 = *(const float4*)(src + q * 8 + 4);
        *(f16x8_t*)(R1c + 65536 + prow * 128 + ((phalf * 64 + q * 16) ^ swz)) = cvt2(a0, a1);
      }
    }
    __syncthreads();

    for (int s = 0; s < 8; ++s) {
      char* BPc = R1c + (s & 1) * 32768;
      char* Yc = R1c + 65536 + (s & 1) * 32768;
      f16x8_t pre_bp[4];
      float4 pre_y[8];
      if (s < 7) {
        int e0n = (s + 1) * 64;
#pragma unroll
        for (int q = 0; q < 4; ++q)
          pre_bp[q] = *(const f16x8_t*)(slab + (size_t)prow * DD + e0n + phalf * 32 + q * 8);
        const float* src = y + (size_t)prow * DD + e0n + phalf * 32;
#pragma unroll
        for (int q = 0; q < 8; ++q) pre_y[q] = *(const float4*)(src + q * 4);
      }
#pragma unroll
      for (int ks = 0; ks < 2; ++ks) {
        f16x8_t aF[4], bF[8];
#pragma unroll
        for (int mf = 0; mf < 4; ++mf) {
          int row = wm * 64 + mf * 16 + lq;
          aF[mf] = *(const f16x8_t*)(Yc + row * 128 +
                     ((ks * 64 + lg * 16) ^ ((unsigned)(row & 7) << 4)));
        }
#pragma unroll
        for (int nf = 0; nf < 8; ++nf) {
          int row = wl * 128 + nf * 16 + lq;
          bF[nf] = *(const f16x8_t*)(BPc + row * 128 +
                     ((ks * 64 + lg * 16) ^ ((unsigned)(row & 7) << 4)));
        }
#pragma unroll
        for (int mf = 0; mf < 4; ++mf)
#pragma unroll
          for (int nf = 0; nf < 8; ++nf)
            accS[mf][nf] = __builtin_amdgcn_mfma_f32_16x16x32_f16(aF[mf], bF[nf], accS[mf][nf], 0, 0, 0);
      }
      if (s < 7) {
        char* BPn = R1c + ((s + 1) & 1) * 32768;
        char* Yn = R1c + 65536 + ((s + 1) & 1) * 32768;
        unsigned swz = (unsigned)(prow & 7) << 4;
#pragma unroll
        for (int q = 0; q < 4; ++q)
          *(f16x8_t*)(BPn + prow * 128 + ((phalf * 64 + q * 16) ^ swz)) = pre_bp[q];
#pragma unroll
        for (int q = 0; q < 4; ++q)
          *(f16x8_t*)(Yn + prow * 128 + ((phalf * 64 + q * 16) ^ swz)) =
              cvt2(pre_y[2 * q], pre_y[2 * q + 1]);
      }
      __syncthreads();
    }

    // ---- softmax over l (per column m) ----
    float red[4][4];
#pragma unroll
    for (int mf = 0; mf < 4; ++mf)
#pragma unroll
      for (int r = 0; r < 4; ++r) {
        float v = accS[mf][0][r];
#pragma unroll
        for (int nf = 1; nf < 8; ++nf) v = fmaxf(v, accS[mf][nf][r]);
        v = fmaxf(v, __shfl_xor(v, 1));
        v = fmaxf(v, __shfl_xor(v, 2));
        v = fmaxf(v, __shfl_xor(v, 4));
        v = fmaxf(v, __shfl_xor(v, 8));
        red[mf][r] = v;
      }
    if (lq == 0) {
#pragma unroll
      for (int mf = 0; mf < 4; ++mf)
#pragma unroll
        for (int r = 0; r < 4; ++r)
          colred[wl * 256 + wm * 64 + mf * 16 + lg * 4 + r] = red[mf][r];
    }
    __syncthreads();
    if (tid < 256) colmax[tid] = fmaxf(colred[tid], colred[256 + tid]);
    __syncthreads();
    float cm[4][4];
#pragma unroll
    for (int mf = 0; mf < 4; ++mf)
#pragma unroll
      for (int r = 0; r < 4; ++r) cm[mf][r] = colmax[wm * 64 + mf * 16 + lg * 4 + r];
    __syncthreads();  // colred reusable
#pragma unroll
    for (int mf = 0; mf < 4; ++mf)
#pragma unroll
      for (int r = 0; r < 4; ++r) {
        float s = 0.f;
#pragma unroll
        for (int nf = 0; nf < 8; ++nf) {
          float p = __expf(accS[mf][nf][r] - cm[mf][r]);
          accS[mf][nf][r] = p;
          s += p;
        }
        s += __shfl_xor(s, 1);
        s += __shfl_xor(s, 2);
        s += __shfl_xor(s, 4);
        s += __shfl_xor(s, 8);
        red[mf][r] = s;
      }
    if (lq == 0) {
#pragma unroll
      for (int mf = 0; mf < 4; ++mf)
#pragma unroll
        for (int r = 0; r < 4; ++r)
          colred[wl * 256 + wm * 64 + mf * 16 + lg * 4 + r] = red[mf][r];
    }
    __syncthreads();
    if (tid < 256) colinv[tid] = 1.f / (colred[tid] + colred[256 + tid]);
    __syncthreads();
    float inv[4][4];
#pragma unroll
    for (int mf = 0; mf < 4; ++mf)
#pragma unroll
      for (int r = 0; r < 4; ++r) inv[mf][r] = colinv[wm * 64 + mf * 16 + lg * 4 + r];
    __syncthreads();  // staging reads all done; region1 becomes A_w
    // writeback A_w[l][m] (b64)
#pragma unroll
    for (int mf = 0; mf < 4; ++mf)
#pragma unroll
      for (int nf = 0; nf < 8; ++nf) {
        int l = wl * 128 + nf * 16 + lq;
        f16x4_t v;
        v[0] = (f16)(accS[mf][nf][0] * inv[mf][0]);
        v[1] = (f16)(accS[mf][nf][1] * inv[mf][1]);
        v[2] = (f16)(accS[mf][nf][2] * inv[mf][2]);
        v[3] = (f16)(accS[mf][nf][3] * inv[mf][3]);
        *(f16x4_t*)(R1c + l * 512 +
                    ((wm * 128 + mf * 32 + lg * 8) ^ ((unsigned)(l & 7) << 4))) = v;
      }
  }
  __syncthreads();

  // ======== phase B: a = A_w @ y ; fused g partials ; a^T -> slab[d][l] ========
  // wave: wl3 = w&3 (l 64-range), wd = w>>2 (d 64-range within dct's 128)
  {
    const int wl3 = wave & 3, wd = wave >> 2;
    float garr[4][4];
#pragma unroll
    for (int lf = 0; lf < 4; ++lf)
#pragma unroll
      for (int r = 0; r < 4; ++r) garr[lf][r] = 0.f;

    const int yd = tid & 127, ymq = tid >> 7;
    f16* const aT = slab;  // alias: P dead

    for (int dct = 0; dct < 4; ++dct) {
      f32x4_t accB[4][4];  // [lf][df]
#pragma unroll
      for (int lf = 0; lf < 4; ++lf)
#pragma unroll
        for (int df = 0; df < 4; ++df) accB[lf][df] = (f32x4_t){0.f, 0.f, 0.f, 0.f};

      float lyA[4][4], lyB[4][4];
      // prologue loads mh=0
#pragma unroll
      for (int q = 0; q < 4; ++q) {
        int m0 = ymq * 16 + q * 4;
#pragma unroll
        for (int k = 0; k < 4; ++k)
          lyA[q][k] = y[(size_t)(m0 + k) * DD + dct * 128 + yd];
      }
#pragma unroll
      for (int mh = 0; mh < 4; ++mh) {
        __syncthreads();  // prev YT reads done
        {
          unsigned swz = (unsigned)(yd & 7) << 4;
#pragma unroll
          for (int q = 0; q < 4; ++q) {
            int m0 = ymq * 16 + q * 4;
            f16x4_t v;
            if (mh & 1) {
              v[0] = (f16)lyB[q][0]; v[1] = (f16)lyB[q][1];
              v[2] = (f16)lyB[q][2]; v[3] = (f16)lyB[q][3];
            } else {
              v[0] = (f16)lyA[q][0]; v[1] = (f16)lyA[q][1];
              v[2] = (f16)lyA[q][2]; v[3] = (f16)lyA[q][3];
            }
            *(f16x4_t*)(R2c + yd * 128 + ((m0 * 2) ^ swz)) = v;
          }
        }
        __syncthreads();
        if (mh < 3) {  // prefetch next mh strided loads (hidden under MFMA)
#pragma unroll
          for (int q = 0; q < 4; ++q) {
            int m0 = (mh + 1) * 64 + ymq * 16 + q * 4;
#pragma unroll
            for (int k = 0; k < 4; ++k) {
              float lv = y[(size_t)(m0 + k) * DD + dct * 128 + yd];
              if (mh & 1) lyA[q][k] = lv; else lyB[q][k] = lv;
            }
          }
        }
#pragma unroll
        for (int ks = 0; ks < 2; ++ks) {
          f16x8_t aF[4], bF[4];
#pragma unroll
          for (int lf = 0; lf < 4; ++lf) {
            int row = wl3 * 64 + lf * 16 + lq;
            aF[lf] = *(const f16x8_t*)(R1c + row * 512 +
                       ((mh * 128 + ks * 64 + lg * 16) ^ ((unsigned)(row & 7) << 4)));
          }
#pragma unroll
          for (int df = 0; df < 4; ++df) {
            int row = wd * 64 + df * 16 + lq;
            bF[df] = *(const f16x8_t*)(R2c + row * 128 +
                       ((ks * 64 + lg * 16) ^ ((unsigned)(row & 7) << 4)));
          }
#pragma unroll
          for (int lf = 0; lf < 4; ++lf)
#pragma unroll
            for (int df = 0; df < 4; ++df)
              accB[lf][df] = __builtin_amdgcn_mfma_f32_16x16x32_f16(aF[lf], bF[df], accB[lf][df], 0, 0, 0);
        }
      }
      // epilogue: g partials + aT writes
      float wvA[4], wvB[4];
#pragma unroll
      for (int df = 0; df < 4; ++df) {
        int d = dct * 128 + wd * 64 + df * 16 + lq;
        wvA[df] = wv[d];
        wvB[df] = wv[DD + d];
      }
#pragma unroll
      for (int lf = 0; lf < 4; ++lf)
#pragma unroll
        for (int r = 0; r < 4; ++r) {
          int l = wl3 * 64 + lf * 16 + lg * 4 + r;
          float gs = 0.f;
#pragma unroll
          for (int df = 0; df < 4; ++df) {
            int d = dct * 128 + wd * 64 + df * 16 + lq;
            float av = accB[lf][df][r];
            float xv = x[(size_t)l * DD + d];
            gs += (xv - av) * wvA[df] + (xv * av) * wvB[df];
          }
          gs += __shfl_xor(gs, 1);
          gs += __shfl_xor(gs, 2);
          gs += __shfl_xor(gs, 4);
          gs += __shfl_xor(gs, 8);
          garr[lf][r] += gs;
        }
#pragma unroll
      for (int lf = 0; lf < 4; ++lf)
#pragma unroll
        for (int df = 0; df < 4; ++df) {
          int d = dct * 128 + wd * 64 + df * 16 + lq;
          int l0 = wl3 * 64 + lf * 16 + lg * 4;
          f16x4_t v;
          v[0] = (f16)accB[lf][df][0]; v[1] = (f16)accB[lf][df][1];
          v[2] = (f16)accB[lf][df][2]; v[3] = (f16)accB[lf][df][3];
          *(f16x4_t*)(aT + (size_t)d * LL + l0) = v;
        }
    }
    __syncthreads();  // YT dead -> region2 becomes gp/beta
    if (lq == 0) {
#pragma unroll
      for (int lf = 0; lf < 4; ++lf)
#pragma unroll
        for (int r = 0; r < 4; ++r)
          gp[wd * 256 + wl3 * 64 + lf * 16 + lg * 4 + r] = garr[lf][r];
    }
  }
  __syncthreads();

  // ======== beta = softmax_l(g) (wave 0) ========
  if (wave == 0) {
    float gv[4];
    float M = -3.4e38f;
#pragma unroll
    for (int q = 0; q < 4; ++q) {
      int l = lane + q * 64;
      gv[q] = gp[l] + gp[256 + l];
      M = fmaxf(M, gv[q]);
    }
#pragma unroll
    for (int s = 1; s < 64; s <<= 1) M = fmaxf(M, __shfl_xor(M, s));
    float S = 0.f, ev[4];
#pragma unroll
    for (int q = 0; q < 4; ++q) { ev[q] = __expf(gv[q] - M); S += ev[q]; }
#pragma unroll
    for (int s = 1; s < 64; s <<= 1) S += __shfl_xor(S, s);
    float inv = 1.f / S;
#pragma unroll
    for (int q = 0; q < 4; ++q) betas[lane + q * 64] = ev[q] * inv;
  }
  __syncthreads();

  // ======== pooled output ========
  {
    const f16* const aT = slab;
    int dc = tid;
    float s1 = 0.f, s2 = 0.f;
    for (int lb = 0; lb < 32; ++lb) {
      f16x8_t av8 = *(const f16x8_t*)(aT + (size_t)dc * LL + lb * 8);
#pragma unroll
      for (int q = 0; q < 8; ++q) {
        int l = lb * 8 + q;
        float bl = betas[l];
        float av = (float)av8[q];
        float xv = x[(size_t)l * DD + dc];
        s1 += bl * (xv - av);
        s2 += bl * (xv * av);
      }
    }
    size_t o = (size_t)side * (512u * 1024u) + (size_t)b * 1024u;
    out[o + dc] = s1;
    out[o + DD + dc] = s2;
  }
}

extern "C" void kernel_launch(void* const* d_in, const int* in_sizes, int n_in,
                              void* d_out, int out_size, void* d_ws, size_t ws_size,
                              hipStream_t stream) {
  (void)in_sizes; (void)n_in; (void)out_size; (void)ws_size;
  const float* gi = (const float*)d_in[0];
  const float* gj = (const float*)d_in[1];
  const float* W  = (const float*)d_in[2];
  const float* wv = (const float*)d_in[3];
  float* out = (float*)d_out;
  f16* Wt = (f16*)d_ws;                 // 512x512 f16 = 512 KiB
  f16* slabs = Wt + DD * DD;            // 1024 slabs x 256 KiB (P, aliased as aT)
  k_prep<<<dim3(64), dim3(256), 0, stream>>>(W, Wt);
  k_main<<<dim3(1024), dim3(512), 0, stream>>>(gi, gj, Wt, wv, slabs, out);
}

// Round 4
// 947.014 us; speedup vs baseline: 1.2870x; 1.2870x over previous
//
#include <hip/hip_runtime.h>

#define LL 256
#define DD 512

typedef _Float16 f16;
typedef _Float16 f16x4_t __attribute__((ext_vector_type(4)));
typedef _Float16 f16x8_t __attribute__((ext_vector_type(8)));
typedef float f32x4_t __attribute__((ext_vector_type(4)));

__device__ __forceinline__ f16x8_t cvt2(const float4 a, const float4 b) {
  f16x8_t v;
  v[0] = (f16)a.x; v[1] = (f16)a.y; v[2] = (f16)a.z; v[3] = (f16)a.w;
  v[4] = (f16)b.x; v[5] = (f16)b.y; v[6] = (f16)b.z; v[7] = (f16)b.w;
  return v;
}

// async global->LDS, 16B per lane; LDS dest = wave-uniform base + lane*16
__device__ __forceinline__ void gl16(const void* g, void* l) {
  __builtin_amdgcn_global_load_lds(
      (const __attribute__((address_space(1))) void*)g,
      (__attribute__((address_space(3))) void*)l, 16, 0, 0);
}

// ---------------- prep: Wt[e][d] = (f16) W[d][e] ----------------
__global__ void k_prep(const float* __restrict__ W, f16* __restrict__ Wt) {
  __shared__ float t[64][65];
  int bx = blockIdx.x & 7;   // e tile
  int by = blockIdx.x >> 3;  // d tile
  int tx = threadIdx.x & 63, tg = threadIdx.x >> 6;
  for (int r = tg; r < 64; r += 4)
    t[r][tx] = W[(by * 64 + r) * DD + bx * 64 + tx];
  __syncthreads();
  for (int r = tg; r < 64; r += 4)
    Wt[(bx * 64 + r) * DD + by * 64 + tx] = (f16)t[tx][r];
}

// LDS region1 (128KB), time-shared:
//   phase 0: xb[2][128][64] f16 (2x16KB)
//   phase A: BP[2][256][64] @0,32768 (via global_load_lds); Y[2][256][64] @65536,98304
//   phase A end..B: A_w[256 l][256 m] f16 (rows 512B, XOR-swizzled)
// LDS region2 (16KB): phase A softmax colred/colmax/colinv; phase B YT[128][64]; then gp/beta

__global__ __launch_bounds__(512, 2)
void k_main(const float* __restrict__ gi, const float* __restrict__ gj,
            const f16* __restrict__ Wt, const float* __restrict__ wv,
            f16* __restrict__ slabs, float* __restrict__ out) {
  __shared__ __align__(16) char R1[131072];
  __shared__ __align__(16) char R2[16384];

  const int tid = threadIdx.x;
  const int lane = tid & 63;
  const int wave = tid >> 6;  // 0..7
  const int lq = lane & 15, lg = lane >> 4;

  const int sb = blockIdx.x;
  const int wk = (sb & 7) * 128 + (sb >> 3);  // XCD swizzle (bijective, 1024%8==0)
  const int b = wk >> 1, side = wk & 1;
  const float* __restrict__ x = (side ? gj : gi) + (size_t)b * (LL * DD);
  const float* __restrict__ y = (side ? gi : gj) + (size_t)b * (LL * DD);
  f16* __restrict__ slab = slabs + (size_t)wk * (LL * DD);  // P (swizzled rows), then a[l][d]

  char* const R1c = R1;
  char* const R2c = R2;
  float* const colred = (float*)R2c;            // [2][256]
  float* const colmax = (float*)(R2c + 2048);
  float* const colinv = (float*)(R2c + 3072);
  float* const gp     = (float*)R2c;            // [2][256] (after YT dead)
  float* const betas  = (float*)(R2c + 2048);

  // ============ phase 0: P = x @ W -> slab (f16, per-128B-chunk XOR-baked) ============
  // mfma(A = x rows l, B = Wt rows e): acc(l = reg, e = lq)
  {
    const int wl2 = wave & 1, we4 = wave >> 1;
    for (int lh = 0; lh < 2; ++lh) {
      f32x4_t acc[4][8];  // [lf][ef]
#pragma unroll
      for (int lf = 0; lf < 4; ++lf)
#pragma unroll
        for (int ef = 0; ef < 8; ++ef) acc[lf][ef] = (f32x4_t){0.f, 0.f, 0.f, 0.f};

      const int xrow = tid >> 2;
      const int xc4 = (tid & 3) * 16;
      {
        const float* src = x + (size_t)(lh * 128 + xrow) * DD + xc4;
        float4 a0 = *(const float4*)src, a1 = *(const float4*)(src + 4);
        float4 a2 = *(const float4*)(src + 8), a3 = *(const float4*)(src + 12);
        unsigned swz = (unsigned)(xrow & 7) << 4;
        *(f16x8_t*)(R1c + xrow * 128 + ((xc4 * 2) ^ swz)) = cvt2(a0, a1);
        *(f16x8_t*)(R1c + xrow * 128 + ((xc4 * 2 + 16) ^ swz)) = cvt2(a2, a3);
      }
      __syncthreads();

      for (int s = 0; s < 8; ++s) {
        char* xbc = R1c + (s & 1) * 16384;
        char* xbn = R1c + ((s + 1) & 1) * 16384;
        float4 p0, p1, p2, p3;
        if (s < 7) {
          const float* src = x + (size_t)(lh * 128 + xrow) * DD + (s + 1) * 64 + xc4;
          p0 = *(const float4*)src; p1 = *(const float4*)(src + 4);
          p2 = *(const float4*)(src + 8); p3 = *(const float4*)(src + 12);
        }
#pragma unroll
        for (int ks = 0; ks < 2; ++ks) {
          f16x8_t aF[4], bF[8];
#pragma unroll
          for (int lf = 0; lf < 4; ++lf) {
            int row = wl2 * 64 + lf * 16 + lq;
            aF[lf] = *(const f16x8_t*)(xbc + row * 128 +
                       ((ks * 64 + lg * 16) ^ ((unsigned)(row & 7) << 4)));
          }
#pragma unroll
          for (int ef = 0; ef < 8; ++ef) {
            int er = we4 * 128 + ef * 16 + lq;
            bF[ef] = *(const f16x8_t*)(Wt + (size_t)er * DD + s * 64 + ks * 32 + lg * 8);
          }
#pragma unroll
          for (int lf = 0; lf < 4; ++lf)
#pragma unroll
            for (int ef = 0; ef < 8; ++ef)
              acc[lf][ef] = __builtin_amdgcn_mfma_f32_16x16x32_f16(aF[lf], bF[ef], acc[lf][ef], 0, 0, 0);
        }
        if (s < 7) {
          unsigned swz = (unsigned)(xrow & 7) << 4;
          *(f16x8_t*)(xbn + xrow * 128 + ((xc4 * 2) ^ swz)) = cvt2(p0, p1);
          *(f16x8_t*)(xbn + xrow * 128 + ((xc4 * 2 + 16) ^ swz)) = cvt2(p2, p3);
        }
        __syncthreads();
      }
      // writeback: dense scalar f16 (16 lanes = 32B contiguous), XOR baked per 128B chunk
#pragma unroll
      for (int lf = 0; lf < 4; ++lf)
#pragma unroll
        for (int ef = 0; ef < 8; ++ef) {
          int e = we4 * 128 + ef * 16 + lq;
          int l0 = lh * 128 + wl2 * 64 + lf * 16 + lg * 4;
#pragma unroll
          for (int r = 0; r < 4; ++r) {
            int l = l0 + r;
            size_t byte = (size_t)l * 1024 + (size_t)(e >> 6) * 128 +
                          (unsigned)(((e & 63) * 2) ^ ((l & 7) << 4));
            *(f16*)((char*)slab + byte) = (f16)acc[lf][ef][r];
          }
        }
    }
  }
  __threadfence_block();
  __syncthreads();

  // ============ phase A: St = y @ P^T, acc(m = reg, l = lq), full S in regs ============
  {
    const int wm = wave & 3, wl = wave >> 2;
    f32x4_t accS[4][8];  // [mf][nf]
#pragma unroll
    for (int mf = 0; mf < 4; ++mf)
#pragma unroll
      for (int nf = 0; nf < 8; ++nf) accS[mf][nf] = (f32x4_t){0.f, 0.f, 0.f, 0.f};

    const int prow = tid >> 1, phalf = tid & 1;
    const int lsub = lane >> 3, lin8 = lane & 7;

    // stage BP(s) via global_load_lds (linear LDS; slab is pre-XOR'd so ds_read XORs)
    auto stageBP = [&](int s, int buf) {
#pragma unroll
      for (int q = 0; q < 4; ++q) {
        int lrow = (q * 8 + wave) * 8 + lsub;
        const char* g = (const char*)slab + (size_t)lrow * 1024 + (size_t)s * 128 + lin8 * 16;
        gl16(g, R1c + buf * 32768 + (q * 8 + wave) * 1024);
      }
    };

    // prologue: stage s=0
    stageBP(0, 0);
    {
      unsigned swz = (unsigned)(prow & 7) << 4;
      const float* src = y + (size_t)prow * DD + phalf * 32;
#pragma unroll
      for (int q = 0; q < 4; ++q) {
        float4 a0 = *(const float4*)(src + q * 8);
        float4 a1 = *(const float4*)(src + q * 8 + 4);
        *(f16x8_t*)(R1c + 65536 + prow * 128 + ((phalf * 64 + q * 16) ^ swz)) = cvt2(a0, a1);
      }
    }
    __syncthreads();

    for (int s = 0; s < 8; ++s) {
      const char* BPc = R1c + (s & 1) * 32768;
      const char* Yc = R1c + 65536 + (s & 1) * 32768;
      float4 pre_y[8];
      if (s < 7) {
        stageBP(s + 1, (s + 1) & 1);
        const float* src = y + (size_t)prow * DD + (s + 1) * 64 + phalf * 32;
#pragma unroll
        for (int q = 0; q < 8; ++q) pre_y[q] = *(const float4*)(src + q * 4);
      }
#pragma unroll
      for (int ks = 0; ks < 2; ++ks) {
        f16x8_t aF[4], bF[8];
#pragma unroll
        for (int mf = 0; mf < 4; ++mf) {
          int row = wm * 64 + mf * 16 + lq;
          aF[mf] = *(const f16x8_t*)(Yc + row * 128 +
                     ((ks * 64 + lg * 16) ^ ((unsigned)(row & 7) << 4)));
        }
#pragma unroll
        for (int nf = 0; nf < 8; ++nf) {
          int row = wl * 128 + nf * 16 + lq;
          bF[nf] = *(const f16x8_t*)(BPc + row * 128 +
                     ((ks * 64 + lg * 16) ^ ((unsigned)(row & 7) << 4)));
        }
#pragma unroll
        for (int mf = 0; mf < 4; ++mf)
#pragma unroll
          for (int nf = 0; nf < 8; ++nf)
            accS[mf][nf] = __builtin_amdgcn_mfma_f32_16x16x32_f16(aF[mf], bF[nf], accS[mf][nf], 0, 0, 0);
      }
      if (s < 7) {
        char* Yn = R1c + 65536 + ((s + 1) & 1) * 32768;
        unsigned swz = (unsigned)(prow & 7) << 4;
#pragma unroll
        for (int q = 0; q < 4; ++q)
          *(f16x8_t*)(Yn + prow * 128 + ((phalf * 64 + q * 16) ^ swz)) =
              cvt2(pre_y[2 * q], pre_y[2 * q + 1]);
      }
      __syncthreads();
    }

    // ---- softmax over l (per column m) ----
    float red[4][4];
#pragma unroll
    for (int mf = 0; mf < 4; ++mf)
#pragma unroll
      for (int r = 0; r < 4; ++r) {
        float v = accS[mf][0][r];
#pragma unroll
        for (int nf = 1; nf < 8; ++nf) v = fmaxf(v, accS[mf][nf][r]);
        v = fmaxf(v, __shfl_xor(v, 1));
        v = fmaxf(v, __shfl_xor(v, 2));
        v = fmaxf(v, __shfl_xor(v, 4));
        v = fmaxf(v, __shfl_xor(v, 8));
        red[mf][r] = v;
      }
    if (lq == 0) {
#pragma unroll
      for (int mf = 0; mf < 4; ++mf)
#pragma unroll
        for (int r = 0; r < 4; ++r)
          colred[wl * 256 + wm * 64 + mf * 16 + lg * 4 + r] = red[mf][r];
    }
    __syncthreads();
    if (tid < 256) colmax[tid] = fmaxf(colred[tid], colred[256 + tid]);
    __syncthreads();
    float cm[4][4];
#pragma unroll
    for (int mf = 0; mf < 4; ++mf)
#pragma unroll
      for (int r = 0; r < 4; ++r) cm[mf][r] = colmax[wm * 64 + mf * 16 + lg * 4 + r];
    __syncthreads();
#pragma unroll
    for (int mf = 0; mf < 4; ++mf)
#pragma unroll
      for (int r = 0; r < 4; ++r) {
        float s = 0.f;
#pragma unroll
        for (int nf = 0; nf < 8; ++nf) {
          float p = __expf(accS[mf][nf][r] - cm[mf][r]);
          accS[mf][nf][r] = p;
          s += p;
        }
        s += __shfl_xor(s, 1);
        s += __shfl_xor(s, 2);
        s += __shfl_xor(s, 4);
        s += __shfl_xor(s, 8);
        red[mf][r] = s;
      }
    if (lq == 0) {
#pragma unroll
      for (int mf = 0; mf < 4; ++mf)
#pragma unroll
        for (int r = 0; r < 4; ++r)
          colred[wl * 256 + wm * 64 + mf * 16 + lg * 4 + r] = red[mf][r];
    }
    __syncthreads();
    if (tid < 256) colinv[tid] = 1.f / (colred[tid] + colred[256 + tid]);
    __syncthreads();
    float inv[4][4];
#pragma unroll
    for (int mf = 0; mf < 4; ++mf)
#pragma unroll
      for (int r = 0; r < 4; ++r) inv[mf][r] = colinv[wm * 64 + mf * 16 + lg * 4 + r];
    __syncthreads();  // all staging reads done; region1 becomes A_w
#pragma unroll
    for (int mf = 0; mf < 4; ++mf)
#pragma unroll
      for (int nf = 0; nf < 8; ++nf) {
        int l = wl * 128 + nf * 16 + lq;
        f16x4_t v;
        v[0] = (f16)(accS[mf][nf][0] * inv[mf][0]);
        v[1] = (f16)(accS[mf][nf][1] * inv[mf][1]);
        v[2] = (f16)(accS[mf][nf][2] * inv[mf][2]);
        v[3] = (f16)(accS[mf][nf][3] * inv[mf][3]);
        *(f16x4_t*)(R1c + l * 512 +
                    ((wm * 128 + mf * 32 + lg * 8) ^ ((unsigned)(l & 7) << 4))) = v;
      }
  }
  __syncthreads();

  // ============ phase B: a = A_w @ y; g partials; a -> slab[l][d] dense ============
  {
    const int wl3 = wave & 3, wd = wave >> 2;
    float garr[4][4];
#pragma unroll
    for (int lf = 0; lf < 4; ++lf)
#pragma unroll
      for (int r = 0; r < 4; ++r) garr[lf][r] = 0.f;

    const int yd = tid & 127, ymq = tid >> 7;
    f16* const aT = slab;

    for (int dct = 0; dct < 4; ++dct) {
      f32x4_t accB[4][4];  // [lf][df], acc(l=reg, d=lq)
#pragma unroll
      for (int lf = 0; lf < 4; ++lf)
#pragma unroll
        for (int df = 0; df < 4; ++df) accB[lf][df] = (f32x4_t){0.f, 0.f, 0.f, 0.f};

      float lyA[4][4], lyB[4][4];
#pragma unroll
      for (int q = 0; q < 4; ++q) {
        int m0 = ymq * 16 + q * 4;
#pragma unroll
        for (int k = 0; k < 4; ++k)
          lyA[q][k] = y[(size_t)(m0 + k) * DD + dct * 128 + yd];
      }
#pragma unroll
      for (int mh = 0; mh < 4; ++mh) {
        __syncthreads();
        {
          unsigned swz = (unsigned)(yd & 7) << 4;
#pragma unroll
          for (int q = 0; q < 4; ++q) {
            int m0 = ymq * 16 + q * 4;
            f16x4_t v;
            if (mh & 1) {
              v[0] = (f16)lyB[q][0]; v[1] = (f16)lyB[q][1];
              v[2] = (f16)lyB[q][2]; v[3] = (f16)lyB[q][3];
            } else {
              v[0] = (f16)lyA[q][0]; v[1] = (f16)lyA[q][1];
              v[2] = (f16)lyA[q][2]; v[3] = (f16)lyA[q][3];
            }
            *(f16x4_t*)(R2c + yd * 128 + ((m0 * 2) ^ swz)) = v;
          }
        }
        __syncthreads();
        if (mh < 3) {
#pragma unroll
          for (int q = 0; q < 4; ++q) {
            int m0 = (mh + 1) * 64 + ymq * 16 + q * 4;
#pragma unroll
            for (int k = 0; k < 4; ++k) {
              float lv = y[(size_t)(m0 + k) * DD + dct * 128 + yd];
              if (mh & 1) lyA[q][k] = lv; else lyB[q][k] = lv;
            }
          }
        }
#pragma unroll
        for (int ks = 0; ks < 2; ++ks) {
          f16x8_t aF[4], bF[4];
#pragma unroll
          for (int lf = 0; lf < 4; ++lf) {
            int row = wl3 * 64 + lf * 16 + lq;
            aF[lf] = *(const f16x8_t*)(R1c + row * 512 +
                       ((mh * 128 + ks * 64 + lg * 16) ^ ((unsigned)(row & 7) << 4)));
          }
#pragma unroll
          for (int df = 0; df < 4; ++df) {
            int row = wd * 64 + df * 16 + lq;
            bF[df] = *(const f16x8_t*)(R2c + row * 128 +
                       ((ks * 64 + lg * 16) ^ ((unsigned)(row & 7) << 4)));
          }
#pragma unroll
          for (int lf = 0; lf < 4; ++lf)
#pragma unroll
            for (int df = 0; df < 4; ++df)
              accB[lf][df] = __builtin_amdgcn_mfma_f32_16x16x32_f16(aF[lf], bF[df], accB[lf][df], 0, 0, 0);
        }
      }
      // epilogue: g partials + dense a writes (lq spans 16 consecutive d)
      float wvA[4], wvB[4];
#pragma unroll
      for (int df = 0; df < 4; ++df) {
        int d = dct * 128 + wd * 64 + df * 16 + lq;
        wvA[df] = wv[d];
        wvB[df] = wv[DD + d];
      }
#pragma unroll
      for (int lf = 0; lf < 4; ++lf)
#pragma unroll
        for (int r = 0; r < 4; ++r) {
          int l = wl3 * 64 + lf * 16 + lg * 4 + r;
          float gs = 0.f;
#pragma unroll
          for (int df = 0; df < 4; ++df) {
            int d = dct * 128 + wd * 64 + df * 16 + lq;
            float av = accB[lf][df][r];
            float xv = x[(size_t)l * DD + d];
            gs += (xv - av) * wvA[df] + (xv * av) * wvB[df];
            aT[(size_t)l * DD + d] = (f16)av;
          }
          gs += __shfl_xor(gs, 1);
          gs += __shfl_xor(gs, 2);
          gs += __shfl_xor(gs, 4);
          gs += __shfl_xor(gs, 8);
          garr[lf][r] += gs;
        }
    }
    __syncthreads();  // YT dead -> region2 becomes gp/beta
    if (lq == 0) {
#pragma unroll
      for (int lf = 0; lf < 4; ++lf)
#pragma unroll
        for (int r = 0; r < 4; ++r)
          gp[wd * 256 + wl3 * 64 + lf * 16 + lg * 4 + r] = garr[lf][r];
    }
  }
  __threadfence_block();
  __syncthreads();

  // ============ beta = softmax_l(g) (wave 0) ============
  if (wave == 0) {
    float gv[4];
    float M = -3.4e38f;
#pragma unroll
    for (int q = 0; q < 4; ++q) {
      int l = lane + q * 64;
      gv[q] = gp[l] + gp[256 + l];
      M = fmaxf(M, gv[q]);
    }
#pragma unroll
    for (int s = 1; s < 64; s <<= 1) M = fmaxf(M, __shfl_xor(M, s));
    float S = 0.f, ev[4];
#pragma unroll
    for (int q = 0; q < 4; ++q) { ev[q] = __expf(gv[q] - M); S += ev[q]; }
#pragma unroll
    for (int s = 1; s < 64; s <<= 1) S += __shfl_xor(S, s);
    float inv = 1.f / S;
#pragma unroll
    for (int q = 0; q < 4; ++q) betas[lane + q * 64] = ev[q] * inv;
  }
  __syncthreads();

  // ============ pooled output ============
  {
    const f16* const aT = slab;
    int dc = tid;
    float s1 = 0.f, s2 = 0.f;
    for (int l = 0; l < 256; ++l) {
      float bl = betas[l];
      float av = (float)aT[(size_t)l * DD + dc];
      float xv = x[(size_t)l * DD + dc];
      s1 += bl * (xv - av);
      s2 += bl * (xv * av);
    }
    size_t o = (size_t)side * (512u * 1024u) + (size_t)b * 1024u;
    out[o + dc] = s1;
    out[o + DD + dc] = s2;
  }
}

extern "C" void kernel_launch(void* const* d_in, const int* in_sizes, int n_in,
                              void* d_out, int out_size, void* d_ws, size_t ws_size,
                              hipStream_t stream) {
  (void)in_sizes; (void)n_in; (void)out_size; (void)ws_size;
  const float* gi = (const float*)d_in[0];
  const float* gj = (const float*)d_in[1];
  const float* W  = (const float*)d_in[2];
  const float* wv = (const float*)d_in[3];
  float* out = (float*)d_out;
  f16* Wt = (f16*)d_ws;                 // 512x512 f16 = 512 KiB
  f16* slabs = Wt + DD * DD;            // 1024 slabs x 256 KiB (P swizzled, then a)
  k_prep<<<dim3(64), dim3(256), 0, stream>>>(W, Wt);
  k_main<<<dim3(1024), dim3(512), 0, stream>>>(gi, gj, Wt, wv, slabs, out);
}